// Round 1
// baseline (650.177 us; speedup 1.0000x reference)
//
#include <hip/hip_runtime.h>

// SwitchHeadCore: B=2,S=2048,D=1024,H=8,E=8,P=128,K=2(top-k)
// tokens T = 4096.  SCALE = 1/sqrt(128)

typedef unsigned short u16;
typedef __attribute__((ext_vector_type(8))) short s8v;   // 8 x bf16 (MFMA A/B frag)
typedef __attribute__((ext_vector_type(4))) float f4v;   // MFMA C/D frag
typedef __attribute__((ext_vector_type(4))) unsigned short us4;

#define ATT_SCALE 0.08838834764831845f

__device__ inline u16 bf16_rne(float f) {
  union { float f; unsigned u; } v; v.f = f;
  unsigned r = v.u + 0x7fffu + ((v.u >> 16) & 1u);
  return (u16)(r >> 16);
}
__device__ inline float bf2f(u16 h) {
  union { unsigned u; float f; } v; v.u = ((unsigned)h) << 16;
  return v.f;
}

// ---------------- weight prep ----------------
// q_w,k_w: [1024][1024] f32 -> bf16 (same layout; already [n][k] for B^T GEMM)
__global__ void conv_qk(const float* __restrict__ Q, const float* __restrict__ K,
                        u16* __restrict__ Qb, u16* __restrict__ Kb) {
  int i = blockIdx.x * 256 + threadIdx.x;  // float4 index over 2*1048576/4
  const float* src; u16* dst; int off;
  if (i < 262144) { src = Q; dst = Qb; off = i; }
  else            { src = K; dst = Kb; off = i - 262144; }
  float4 v = *(const float4*)&src[(size_t)off * 4];
  us4 o; o[0]=bf16_rne(v.x); o[1]=bf16_rne(v.y); o[2]=bf16_rne(v.z); o[3]=bf16_rne(v.w);
  *(us4*)&dst[(size_t)off * 4] = o;
}

// mode 0: v_w [he][1024 d][128 p] -> vwT [h][p][e][d]   (B rows p, k = e*1024+d)
// mode 1: o_w [he][128 p][1024 d] -> owT [d][he*128+p]  (B rows d, k = he*128+p)
__global__ void transpose_w(const float* __restrict__ src, u16* __restrict__ dst, int mode) {
  __shared__ float tile[32][33];
  int he = blockIdx.z;
  int C = mode ? 1024 : 128;
  int r0 = blockIdx.y * 32, c0 = blockIdx.x * 32;
  int lc = threadIdx.x & 31, rr = threadIdx.x >> 5;
  const float* s = src + (size_t)he * 131072;
#pragma unroll
  for (int i = 0; i < 4; ++i) {
    int r = rr + i * 8;
    tile[r][lc] = s[(size_t)(r0 + r) * C + c0 + lc];
  }
  __syncthreads();
#pragma unroll
  for (int i = 0; i < 4; ++i) {
    int c = rr + i * 8;
    float v = tile[lc][c];
    size_t a;
    if (mode) a = (size_t)(c0 + c) * 8192 + (size_t)he * 128 + (r0 + lc);
    else      a = (size_t)(he >> 3) * 1048576 + (size_t)(c0 + c) * 8192 + (size_t)(he & 7) * 1024 + (r0 + lc);
    dst[a] = bf16_rne(v);
  }
}

// ---------------- routing + x->bf16 ----------------
// 8 tokens/block. Computes sigmoid top-2 gates for sel_v and sel_o, dense [t][64] f32.
__global__ __launch_bounds__(256, 2) void routing(
    const float* __restrict__ X, const float* __restrict__ SelV, const float* __restrict__ SelO,
    const float* __restrict__ RS, float* __restrict__ GateV, float* __restrict__ GateO,
    u16* __restrict__ Xb) {
  __shared__ float xs[8][1024];
  __shared__ float lgs[8][128];
  int t0 = blockIdx.x * 8;
  int tid = threadIdx.x;
  for (int i = tid; i < 2048; i += 256) {   // float4 units: 8 rows * 256
    int row = i >> 8, c = (i & 255) * 4;
    float4 v = *(const float4*)&X[(size_t)(t0 + row) * 1024 + c];
    *(float4*)&xs[row][c] = v;
    us4 o; o[0]=bf16_rne(v.x); o[1]=bf16_rne(v.y); o[2]=bf16_rne(v.z); o[3]=bf16_rne(v.w);
    *(us4*)&Xb[(size_t)(t0 + row) * 1024 + c] = o;
  }
  __syncthreads();
  {
    int widx = tid & 127, tg = tid >> 7;   // 128 logit rows, 2 token-groups of 4
    const float* w = (widx < 64) ? (SelV + (size_t)widx * 1024) : (SelO + (size_t)(widx - 64) * 1024);
    float acc[4] = {0.f, 0.f, 0.f, 0.f};
    for (int k = 0; k < 1024; k += 4) {
      float4 wv = *(const float4*)&w[k];
#pragma unroll
      for (int t = 0; t < 4; ++t) {
        float4 xv = *(const float4*)&xs[tg * 4 + t][k];
        acc[t] += wv.x * xv.x + wv.y * xv.y + wv.z * xv.z + wv.w * xv.w;
      }
    }
#pragma unroll
    for (int t = 0; t < 4; ++t) lgs[tg * 4 + t][widx] = acc[t];
  }
  __syncthreads();
  if (tid < 128) {
    float rs = RS[0];
    int tok = tid >> 4, which = (tid >> 3) & 1, h = tid & 7;
    float p[8];
#pragma unroll
    for (int e = 0; e < 8; ++e)
      p[e] = 1.f / (1.f + __expf(-lgs[tok][which * 64 + h * 8 + e]));
    float v1 = -1.f; int i1 = -1;
#pragma unroll
    for (int e = 0; e < 8; ++e) if (p[e] > v1) { v1 = p[e]; i1 = e; }
    float v2 = -1.f; int i2 = -1;
#pragma unroll
    for (int e = 0; e < 8; ++e) if (e != i1 && p[e] > v2) { v2 = p[e]; i2 = e; }
    float ssum = fmaxf(v1 + v2, 1e-9f);
    float g1 = v1 / ssum * rs, g2 = v2 / ssum * rs;
    float* G = which ? GateO : GateV;
#pragma unroll
    for (int e = 0; e < 8; ++e)
      G[(size_t)(t0 + tok) * 64 + h * 8 + e] = (e == i1) ? g1 : ((e == i2) ? g2 : 0.f);
  }
}

// ---------------- Q/K projection GEMM ----------------
// C[t, hp] = sum_d X[t,d]*W[hp,d]; out stored [b][h][s][p] bf16. grid (32, 8, 2)
__global__ __launch_bounds__(256, 2) void gemm_qk(
    const u16* __restrict__ Xb, const u16* __restrict__ Wq, const u16* __restrict__ Wk,
    u16* __restrict__ Qo, u16* __restrict__ Ko) {
  __shared__ u16 At[128 * 40];
  __shared__ u16 Bt[128 * 40];
  const int tb = blockIdx.x, nb = blockIdx.y;
  const u16* W = blockIdx.z ? Wk : Wq;
  u16* Out = blockIdx.z ? Ko : Qo;
  const int tid = threadIdx.x;
  const int wave = tid >> 6, lane = tid & 63;
  const int wm = wave >> 1, wn = wave & 1;
  const int lg = lane >> 4, lr = lane & 15;
  f4v acc[4][4] = {};
  for (int kt = 0; kt < 32; ++kt) {
    __syncthreads();
#pragma unroll
    for (int i = 0; i < 2; ++i) {
      int idx = tid + i * 256;
      int r = idx >> 2, c8 = (idx & 3) << 3;
      *(s8v*)&At[r * 40 + c8] = *(const s8v*)&Xb[(size_t)(tb * 128 + r) * 1024 + kt * 32 + c8];
      *(s8v*)&Bt[r * 40 + c8] = *(const s8v*)&W[(size_t)(nb * 128 + r) * 1024 + kt * 32 + c8];
    }
    __syncthreads();
    s8v af[4], bfr[4];
#pragma unroll
    for (int m = 0; m < 4; ++m) af[m] = *(const s8v*)&At[(wm * 64 + m * 16 + lr) * 40 + lg * 8];
#pragma unroll
    for (int n = 0; n < 4; ++n) bfr[n] = *(const s8v*)&Bt[(wn * 64 + n * 16 + lr) * 40 + lg * 8];
#pragma unroll
    for (int m = 0; m < 4; ++m)
#pragma unroll
      for (int n = 0; n < 4; ++n)
        acc[m][n] = __builtin_amdgcn_mfma_f32_16x16x32_bf16(af[m], bfr[n], acc[m][n], 0, 0, 0);
  }
#pragma unroll
  for (int m = 0; m < 4; ++m) {
    int tbase = tb * 128 + wm * 64 + m * 16 + lg * 4;
    int b = tbase >> 11, s = tbase & 2047;
#pragma unroll
    for (int n = 0; n < 4; ++n) {
      int p = wn * 64 + n * 16 + lr;
      size_t base = ((size_t)(b * 8 + nb) * 2048 + s) * 128 + p;
#pragma unroll
      for (int j = 0; j < 4; ++j)
        Out[base + (size_t)j * 128] = bf16_rne(acc[m][n][j]);
    }
  }
}

// ---------------- V expert projection GEMM (gate folded into A staging) ----------------
// v[t,h,p] = sum_{e,d} (gate_v[t,h,e]*x[t,d]) * v_w[h,e,d,p]; K = 8192.
// Output stored TRANSPOSED: VT[((b*8+h)*128+p)*2048 + s]  (keys contiguous, for attention PV)
__global__ __launch_bounds__(256, 2) void gemm_v(
    const u16* __restrict__ Xb, const u16* __restrict__ Vw /*[h][p][e][d]*/,
    const float* __restrict__ GateV, u16* __restrict__ VT) {
  __shared__ u16 At[128 * 40];
  __shared__ u16 Bt[128 * 40];
  __shared__ float gsh[128 * 8];
  const int tb = blockIdx.x, h = blockIdx.y;
  const int tid = threadIdx.x;
  for (int i = tid; i < 1024; i += 256) {
    int r = i >> 3, e = i & 7;
    gsh[i] = GateV[(size_t)(tb * 128 + r) * 64 + h * 8 + e];
  }
  const int wave = tid >> 6, lane = tid & 63;
  const int wm = wave >> 1, wn = wave & 1;
  const int lg = lane >> 4, lr = lane & 15;
  f4v acc[4][4] = {};
  for (int kt = 0; kt < 256; ++kt) {
    const int e = kt >> 5, d0 = (kt & 31) * 32;
    __syncthreads();
#pragma unroll
    for (int i = 0; i < 2; ++i) {
      int idx = tid + i * 256;
      int r = idx >> 2, c8 = (idx & 3) << 3;
      s8v xv = *(const s8v*)&Xb[(size_t)(tb * 128 + r) * 1024 + d0 + c8];
      float g = gsh[r * 8 + e];
      s8v o;
#pragma unroll
      for (int j = 0; j < 8; ++j)
        o[j] = (short)bf16_rne(bf2f((u16)xv[j]) * g);
      *(s8v*)&At[r * 40 + c8] = o;
      *(s8v*)&Bt[r * 40 + c8] = *(const s8v*)&Vw[((size_t)(h * 128 + r) * 8 + e) * 1024 + d0 + c8];
    }
    __syncthreads();
    s8v af[4], bfr[4];
#pragma unroll
    for (int m = 0; m < 4; ++m) af[m] = *(const s8v*)&At[(wm * 64 + m * 16 + lr) * 40 + lg * 8];
#pragma unroll
    for (int n = 0; n < 4; ++n) bfr[n] = *(const s8v*)&Bt[(wn * 64 + n * 16 + lr) * 40 + lg * 8];
#pragma unroll
    for (int m = 0; m < 4; ++m)
#pragma unroll
      for (int n = 0; n < 4; ++n)
        acc[m][n] = __builtin_amdgcn_mfma_f32_16x16x32_bf16(af[m], bfr[n], acc[m][n], 0, 0, 0);
  }
#pragma unroll
  for (int m = 0; m < 4; ++m) {
    int tbase = tb * 128 + wm * 64 + m * 16 + lg * 4;
    int b = tbase >> 11, s = tbase & 2047;
#pragma unroll
    for (int n = 0; n < 4; ++n) {
      int p = wn * 64 + n * 16 + lr;
      us4 pk;
#pragma unroll
      for (int j = 0; j < 4; ++j) pk[j] = bf16_rne(acc[m][n][j]);
      *(us4*)&VT[((size_t)(b * 8 + h) * 128 + p) * 2048 + s] = pk;
    }
  }
}

// ---------------- attention (flash-style, scoresT = mfma(K,Q), ctxT = mfma(Vt,P)) ----------------
// grid (32 qblocks of 64, 16 bh). Each wave owns 16 queries; lane lr owns 1 query.
__global__ __launch_bounds__(256, 2) void attn(
    const u16* __restrict__ Q, const u16* __restrict__ K,
    const u16* __restrict__ VT, u16* __restrict__ CTX) {
  __shared__ u16 Kt[64 * 136];      // [key][p] pad+8
  __shared__ u16 Vt[128 * 72];      // [p][key] pad+8
  __shared__ u16 Pl[4][16 * 72];    // per-wave [q][key] pad+8
  const int qb = blockIdx.x, bh = blockIdx.y;
  const int tid = threadIdx.x;
  const int wave = tid >> 6, lane = tid & 63;
  const int lg = lane >> 4, lr = lane & 15;
  const size_t base = (size_t)bh * 2048 * 128;
  const int q0 = qb * 64 + wave * 16;
  s8v qf[4];
#pragma unroll
  for (int ks = 0; ks < 4; ++ks)
    qf[ks] = *(const s8v*)&Q[base + (size_t)(q0 + lr) * 128 + ks * 32 + lg * 8];
  f4v cacc[8] = {};
  float mrun = -1e30f, ssum = 0.f;
  for (int kb = 0; kb < 32; ++kb) {
    __syncthreads();
#pragma unroll
    for (int i = 0; i < 4; ++i) {
      int idx = tid + i * 256;
      int r = idx >> 4, c8 = (idx & 15) << 3;
      *(s8v*)&Kt[r * 136 + c8] = *(const s8v*)&K[base + (size_t)(kb * 64 + r) * 128 + c8];
    }
#pragma unroll
    for (int i = 0; i < 4; ++i) {
      int idx = tid + i * 256;
      int r = idx >> 3, c8 = (idx & 7) << 3;
      *(s8v*)&Vt[r * 72 + c8] = *(const s8v*)&VT[base + (size_t)r * 2048 + kb * 64 + c8];
    }
    __syncthreads();
    f4v sc[4] = {};
#pragma unroll
    for (int ks = 0; ks < 4; ++ks) {
#pragma unroll
      for (int m = 0; m < 4; ++m) {
        s8v ak = *(const s8v*)&Kt[(m * 16 + lr) * 136 + ks * 32 + lg * 8];
        sc[m] = __builtin_amdgcn_mfma_f32_16x16x32_bf16(ak, qf[ks], sc[m], 0, 0, 0);
      }
    }
    float tmax = -1e30f;
#pragma unroll
    for (int m = 0; m < 4; ++m)
#pragma unroll
      for (int j = 0; j < 4; ++j) {
        float v = sc[m][j] * ATT_SCALE;
        sc[m][j] = v;
        tmax = fmaxf(tmax, v);
      }
    tmax = fmaxf(tmax, __shfl_xor(tmax, 16));
    tmax = fmaxf(tmax, __shfl_xor(tmax, 32));
    float mnew = fmaxf(mrun, tmax);
    float f = __expf(mrun - mnew);
    mrun = mnew;
    float psum = 0.f;
#pragma unroll
    for (int m = 0; m < 4; ++m) {
      us4 pk;
#pragma unroll
      for (int j = 0; j < 4; ++j) {
        float pe = __expf(sc[m][j] - mnew);
        psum += pe;
        pk[j] = bf16_rne(pe);
      }
      *(us4*)&Pl[wave][lr * 72 + m * 16 + lg * 4] = pk;
    }
    psum += __shfl_xor(psum, 16);
    psum += __shfl_xor(psum, 32);
    ssum = ssum * f + psum;
#pragma unroll
    for (int mr = 0; mr < 8; ++mr)
#pragma unroll
      for (int j = 0; j < 4; ++j) cacc[mr][j] *= f;
#pragma unroll
    for (int ks = 0; ks < 2; ++ks) {
      s8v bp = *(const s8v*)&Pl[wave][lr * 72 + ks * 32 + lg * 8];
#pragma unroll
      for (int mr = 0; mr < 8; ++mr) {
        s8v av = *(const s8v*)&Vt[(mr * 16 + lr) * 72 + ks * 32 + lg * 8];
        cacc[mr] = __builtin_amdgcn_mfma_f32_16x16x32_bf16(av, bp, cacc[mr], 0, 0, 0);
      }
    }
  }
  float rinv = 1.f / ssum;
#pragma unroll
  for (int mr = 0; mr < 8; ++mr) {
    us4 pk;
#pragma unroll
    for (int j = 0; j < 4; ++j) pk[j] = bf16_rne(cacc[mr][j] * rinv);
    *(us4*)&CTX[base + (size_t)(q0 + lr) * 128 + mr * 16 + lg * 4] = pk;
  }
}

// ---------------- output expert projection GEMM (gate folded into A staging) ----------------
// out[t,d] = sum_{he,p} (gate_o[t,he]*ctx[t,h,p]) * o_w[he,p,d]; K = 8192. fp32 out.
__global__ __launch_bounds__(256, 2) void gemm_out(
    const u16* __restrict__ CTX, const u16* __restrict__ Ow /*[d][8192]*/,
    const float* __restrict__ GateO, float* __restrict__ OUT) {
  __shared__ u16 At[128 * 40];
  __shared__ u16 Bt[128 * 40];
  __shared__ float gsh[128 * 64];
  const int tb = blockIdx.x, db = blockIdx.y;
  const int tid = threadIdx.x;
  for (int i = tid; i < 8192; i += 256)
    gsh[i] = GateO[(size_t)(tb * 128 + (i >> 6)) * 64 + (i & 63)];
  const int wave = tid >> 6, lane = tid & 63;
  const int wm = wave >> 1, wn = wave & 1;
  const int lg = lane >> 4, lr = lane & 15;
  f4v acc[4][4] = {};
  for (int kt = 0; kt < 256; ++kt) {
    const int he = kt >> 2, p0 = (kt & 3) * 32;
    const int h = he >> 3;
    __syncthreads();
#pragma unroll
    for (int i = 0; i < 2; ++i) {
      int idx = tid + i * 256;
      int r = idx >> 2, c8 = (idx & 3) << 3;
      int t = tb * 128 + r;
      int b = t >> 11, s = t & 2047;
      s8v cv = *(const s8v*)&CTX[((size_t)(b * 8 + h) * 2048 + s) * 128 + p0 + c8];
      float g = gsh[r * 64 + he];
      s8v o;
#pragma unroll
      for (int j = 0; j < 8; ++j)
        o[j] = (short)bf16_rne(bf2f((u16)cv[j]) * g);
      *(s8v*)&At[r * 40 + c8] = o;
      *(s8v*)&Bt[r * 40 + c8] = *(const s8v*)&Ow[(size_t)(db * 128 + r) * 8192 + kt * 32 + c8];
    }
    __syncthreads();
    s8v af[4], bfr[4];
#pragma unroll
    for (int m = 0; m < 4; ++m) af[m] = *(const s8v*)&At[(wm * 64 + m * 16 + lr) * 40 + lg * 8];
#pragma unroll
    for (int n = 0; n < 4; ++n) bfr[n] = *(const s8v*)&Bt[(wn * 64 + n * 16 + lr) * 40 + lg * 8];
#pragma unroll
    for (int m = 0; m < 4; ++m)
#pragma unroll
      for (int n = 0; n < 4; ++n)
        acc[m][n] = __builtin_amdgcn_mfma_f32_16x16x32_bf16(af[m], bfr[n], acc[m][n], 0, 0, 0);
  }
#pragma unroll
  for (int m = 0; m < 4; ++m) {
    int t = tb * 128 + wm * 64 + m * 16 + lg * 4;
#pragma unroll
    for (int n = 0; n < 4; ++n) {
      int d = db * 128 + wn * 64 + n * 16 + lr;
#pragma unroll
      for (int j = 0; j < 4; ++j)
        OUT[(size_t)(t + j) * 1024 + d] = acc[m][n][j];
    }
  }
}

extern "C" void kernel_launch(void* const* d_in, const int* in_sizes, int n_in,
                              void* d_out, int out_size, void* d_ws, size_t ws_size,
                              hipStream_t stream) {
  const float* x     = (const float*)d_in[0];
  const float* q_w   = (const float*)d_in[1];
  const float* k_w   = (const float*)d_in[2];
  const float* v_w   = (const float*)d_in[3];
  const float* o_w   = (const float*)d_in[4];
  const float* sel_v = (const float*)d_in[5];
  const float* sel_o = (const float*)d_in[6];
  const float* rs    = (const float*)d_in[7];

  char* ws = (char*)d_ws;
  // workspace layout (~78 MB total)
  u16*   xb  = (u16*)(ws);                    // 8 MB  x bf16 [4096][1024]
  u16*   qwb = (u16*)(ws + 8388608);          // 2 MB
  u16*   kwb = (u16*)(ws + 10485760);         // 2 MB
  u16*   vwT = (u16*)(ws + 12582912);         // 16 MB [h][p][e][d]
  u16*   owT = (u16*)(ws + 29360128);         // 16 MB [d][he*128+p]
  float* gv  = (float*)(ws + 46137344);       // 1 MB  [t][64]
  float* go  = (float*)(ws + 47185920);       // 1 MB
  u16*   qh  = (u16*)(ws + 48234496);         // 8 MB  [bh][s][p]
  u16*   kh  = (u16*)(ws + 56623104);         // 8 MB  [bh][s][p]
  u16*   vt  = (u16*)(ws + 65011712);         // 8 MB  [bh][p][s]
  u16*   ctx = (u16*)(ws + 73400320);         // 8 MB  [bh][s][p]
  float* outp = (float*)d_out;

  hipLaunchKernelGGL(conv_qk, dim3(2048), dim3(256), 0, stream, q_w, k_w, qwb, kwb);
  hipLaunchKernelGGL(transpose_w, dim3(4, 32, 64), dim3(256), 0, stream, v_w, vwT, 0);
  hipLaunchKernelGGL(transpose_w, dim3(32, 4, 64), dim3(256), 0, stream, o_w, owT, 1);
  hipLaunchKernelGGL(routing, dim3(512), dim3(256), 0, stream, x, sel_v, sel_o, rs, gv, go, xb);
  hipLaunchKernelGGL(gemm_qk, dim3(32, 8, 2), dim3(256), 0, stream, xb, qwb, kwb, qh, kh);
  hipLaunchKernelGGL(gemm_v, dim3(32, 8), dim3(256), 0, stream, xb, vwT, gv, vt);
  hipLaunchKernelGGL(attn, dim3(32, 16), dim3(256), 0, stream, qh, kh, vt, ctx);
  hipLaunchKernelGGL(gemm_out, dim3(32, 8), dim3(256), 0, stream, ctx, owT, go, outp);
}

// Round 2
// 478.277 us; speedup vs baseline: 1.3594x; 1.3594x over previous
//
#include <hip/hip_runtime.h>

// SwitchHeadCore: B=2,S=2048,D=1024,H=8,E=8,P=128,K=2(top-k). T = 4096.

typedef unsigned short u16;
typedef __attribute__((ext_vector_type(8))) short s8v;   // 8 x bf16 (MFMA A/B frag)
typedef __attribute__((ext_vector_type(4))) float f4v;   // MFMA C/D frag
typedef __attribute__((ext_vector_type(4))) unsigned short us4;

#define ATT_SCALE 0.08838834764831845f

__device__ inline u16 bf16_rne(float f) {
  union { float f; unsigned u; } v; v.f = f;
  unsigned r = v.u + 0x7fffu + ((v.u >> 16) & 1u);
  return (u16)(r >> 16);
}
__device__ inline float bf2f(u16 h) {
  union { unsigned u; float f; } v; v.u = ((unsigned)h) << 16;
  return v.f;
}

// ---------------- weight prep ----------------
__global__ void conv_qk(const float* __restrict__ Q, const float* __restrict__ K,
                        u16* __restrict__ Qb, u16* __restrict__ Kb) {
  int i = blockIdx.x * 256 + threadIdx.x;
  const float* src; u16* dst; int off;
  if (i < 262144) { src = Q; dst = Qb; off = i; }
  else            { src = K; dst = Kb; off = i - 262144; }
  float4 v = *(const float4*)&src[(size_t)off * 4];
  us4 o; o[0]=bf16_rne(v.x); o[1]=bf16_rne(v.y); o[2]=bf16_rne(v.z); o[3]=bf16_rne(v.w);
  *(us4*)&dst[(size_t)off * 4] = o;
}

// mode 0: v_w [he][1024 d][128 p] -> vwT [h][p][e][d]
// mode 1: o_w [he][128 p][1024 d] -> owT [d][he*128+p]
__global__ void transpose_w(const float* __restrict__ src, u16* __restrict__ dst, int mode) {
  __shared__ float tile[32][33];
  int he = blockIdx.z;
  int C = mode ? 1024 : 128;
  int r0 = blockIdx.y * 32, c0 = blockIdx.x * 32;
  int lc = threadIdx.x & 31, rr = threadIdx.x >> 5;
  const float* s = src + (size_t)he * 131072;
#pragma unroll
  for (int i = 0; i < 4; ++i) {
    int r = rr + i * 8;
    tile[r][lc] = s[(size_t)(r0 + r) * C + c0 + lc];
  }
  __syncthreads();
#pragma unroll
  for (int i = 0; i < 4; ++i) {
    int c = rr + i * 8;
    float v = tile[lc][c];
    size_t a;
    if (mode) a = (size_t)(c0 + c) * 8192 + (size_t)he * 128 + (r0 + lc);
    else      a = (size_t)(he >> 3) * 1048576 + (size_t)(c0 + c) * 8192 + (size_t)(he & 7) * 1024 + (r0 + lc);
    dst[a] = bf16_rne(v);
  }
}

// ---------------- routing + x->bf16 ----------------
// V gate: packed top-2 (sorted expert pair + gates). O gate: dense [t][64].
__global__ __launch_bounds__(256, 2) void routing(
    const float* __restrict__ X, const float* __restrict__ SelV, const float* __restrict__ SelO,
    const float* __restrict__ RS, int2* __restrict__ Tvi, float2* __restrict__ Tvg,
    float* __restrict__ GateO, u16* __restrict__ Xb) {
  __shared__ float xs[8][1024];
  __shared__ float lgs[8][128];
  int t0 = blockIdx.x * 8;
  int tid = threadIdx.x;
  for (int i = tid; i < 2048; i += 256) {
    int row = i >> 8, c = (i & 255) * 4;
    float4 v = *(const float4*)&X[(size_t)(t0 + row) * 1024 + c];
    *(float4*)&xs[row][c] = v;
    us4 o; o[0]=bf16_rne(v.x); o[1]=bf16_rne(v.y); o[2]=bf16_rne(v.z); o[3]=bf16_rne(v.w);
    *(us4*)&Xb[(size_t)(t0 + row) * 1024 + c] = o;
  }
  __syncthreads();
  {
    int widx = tid & 127, tg = tid >> 7;
    const float* w = (widx < 64) ? (SelV + (size_t)widx * 1024) : (SelO + (size_t)(widx - 64) * 1024);
    float acc[4] = {0.f, 0.f, 0.f, 0.f};
    for (int k = 0; k < 1024; k += 4) {
      float4 wv = *(const float4*)&w[k];
#pragma unroll
      for (int t = 0; t < 4; ++t) {
        float4 xv = *(const float4*)&xs[tg * 4 + t][k];
        acc[t] += wv.x * xv.x + wv.y * xv.y + wv.z * xv.z + wv.w * xv.w;
      }
    }
#pragma unroll
    for (int t = 0; t < 4; ++t) lgs[tg * 4 + t][widx] = acc[t];
  }
  __syncthreads();
  if (tid < 128) {
    float rs = RS[0];
    int tok = tid >> 4, which = (tid >> 3) & 1, h = tid & 7;
    float p[8];
#pragma unroll
    for (int e = 0; e < 8; ++e)
      p[e] = 1.f / (1.f + __expf(-lgs[tok][which * 64 + h * 8 + e]));
    float v1 = -1.f; int i1 = -1;
#pragma unroll
    for (int e = 0; e < 8; ++e) if (p[e] > v1) { v1 = p[e]; i1 = e; }
    float v2 = -1.f; int i2 = -1;
#pragma unroll
    for (int e = 0; e < 8; ++e) if (e != i1 && p[e] > v2) { v2 = p[e]; i2 = e; }
    float ssum = fmaxf(v1 + v2, 1e-9f);
    float g1 = v1 / ssum * rs, g2 = v2 / ssum * rs;
    int t = t0 + tok;
    if (which) {
#pragma unroll
      for (int e = 0; e < 8; ++e)
        GateO[(size_t)t * 64 + h * 8 + e] = (e == i1) ? g1 : ((e == i2) ? g2 : 0.f);
    } else {
      int lo, hi; float glo, ghi;
      if (i1 < i2) { lo = i1; hi = i2; glo = g1; ghi = g2; }
      else         { lo = i2; hi = i1; glo = g2; ghi = g1; }
      Tvi[t * 8 + h] = make_int2(lo, hi);
      Tvg[t * 8 + h] = make_float2(glo, ghi);
    }
  }
}

// ---------------- V bucket build: bucket = h*28 + pairid(lo,hi) ----------------
__global__ void build_buckets(const int2* __restrict__ Tvi, const float2* __restrict__ Tvg,
                              int* __restrict__ bcnt, int* __restrict__ btok,
                              float2* __restrict__ bgate) {
  int t = blockIdx.x * 256 + threadIdx.x;  // 4096 tokens
#pragma unroll
  for (int h = 0; h < 8; ++h) {
    int2 e = Tvi[t * 8 + h];
    int lo = e.x, hi = e.y;
    int pid = lo * 7 - (lo * (lo - 1)) / 2 + (hi - lo - 1);
    int b = h * 28 + pid;
    int pos = atomicAdd(&bcnt[b], 1);
    if (pos < 1024) {
      btok[b * 1024 + pos] = t;
      bgate[b * 1024 + pos] = Tvg[t * 8 + h];
    }
  }
}

// ---------------- Q/K projection GEMM ----------------
__global__ __launch_bounds__(256, 2) void gemm_qk(
    const u16* __restrict__ Xb, const u16* __restrict__ Wq, const u16* __restrict__ Wk,
    u16* __restrict__ Qo, u16* __restrict__ Ko) {
  __shared__ u16 At[128 * 40];
  __shared__ u16 Bt[128 * 40];
  const int tb = blockIdx.x, nb = blockIdx.y;
  const u16* W = blockIdx.z ? Wk : Wq;
  u16* Out = blockIdx.z ? Ko : Qo;
  const int tid = threadIdx.x;
  const int wave = tid >> 6, lane = tid & 63;
  const int wm = wave >> 1, wn = wave & 1;
  const int lg = lane >> 4, lr = lane & 15;
  f4v acc[4][4] = {};
  for (int kt = 0; kt < 32; ++kt) {
    __syncthreads();
#pragma unroll
    for (int i = 0; i < 2; ++i) {
      int idx = tid + i * 256;
      int r = idx >> 2, c8 = (idx & 3) << 3;
      *(s8v*)&At[r * 40 + c8] = *(const s8v*)&Xb[(size_t)(tb * 128 + r) * 1024 + kt * 32 + c8];
      *(s8v*)&Bt[r * 40 + c8] = *(const s8v*)&W[(size_t)(nb * 128 + r) * 1024 + kt * 32 + c8];
    }
    __syncthreads();
    s8v af[4], bfr[4];
#pragma unroll
    for (int m = 0; m < 4; ++m) af[m] = *(const s8v*)&At[(wm * 64 + m * 16 + lr) * 40 + lg * 8];
#pragma unroll
    for (int n = 0; n < 4; ++n) bfr[n] = *(const s8v*)&Bt[(wn * 64 + n * 16 + lr) * 40 + lg * 8];
#pragma unroll
    for (int m = 0; m < 4; ++m)
#pragma unroll
      for (int n = 0; n < 4; ++n)
        acc[m][n] = __builtin_amdgcn_mfma_f32_16x16x32_bf16(af[m], bfr[n], acc[m][n], 0, 0, 0);
  }
#pragma unroll
  for (int m = 0; m < 4; ++m) {
    int tbase = tb * 128 + wm * 64 + m * 16 + lg * 4;
    int b = tbase >> 11, s = tbase & 2047;
#pragma unroll
    for (int n = 0; n < 4; ++n) {
      int p = wn * 64 + n * 16 + lr;
      size_t base = ((size_t)(b * 8 + nb) * 2048 + s) * 128 + p;
#pragma unroll
      for (int j = 0; j < 4; ++j)
        Out[base + (size_t)j * 128] = bf16_rne(acc[m][n][j]);
    }
  }
}

// ---------------- sparse V expert GEMM (pair buckets, K=2048, M-tile 64) ----------------
// Writes complete v rows -> Vtmp [t][h*128+p] bf16. No atomics; deterministic.
__global__ __launch_bounds__(256, 4) void gemm_v_sparse(
    const u16* __restrict__ Xb, const u16* __restrict__ Vw /*[h][p][e][d]*/,
    const int* __restrict__ bcnt, const int* __restrict__ btok,
    const float2* __restrict__ bgate, u16* __restrict__ Vtmp) {
  const int bucket = blockIdx.y;
  const int h = bucket / 28, pid = bucket % 28;
  const int cnt = min(bcnt[bucket], 512);
  const int tile = blockIdx.x;
  if (tile * 64 >= cnt) return;
  int lo = 0, rem = pid;
  while (rem >= 7 - lo) { rem -= 7 - lo; lo++; }
  const int hi = lo + 1 + rem;
  __shared__ u16 At[64 * 40];
  __shared__ u16 Bt[128 * 40];
  __shared__ int toksh[64];
  __shared__ float g0sh[64], g1sh[64];
  const int tid = threadIdx.x;
  if (tid < 64) {
    int ar = tile * 64 + tid;
    if (ar < cnt) {
      toksh[tid] = btok[bucket * 1024 + ar];
      float2 g = bgate[bucket * 1024 + ar];
      g0sh[tid] = g.x; g1sh[tid] = g.y;
    } else { toksh[tid] = 0; g0sh[tid] = 0.f; g1sh[tid] = 0.f; }
  }
  const int wave = tid >> 6, lane = tid & 63;
  const int lg = lane >> 4, lr = lane & 15;
  f4v acc[4][2] = {};
  const int rA = tid >> 2, cA = (tid & 3) << 3;
  for (int kt = 0; kt < 64; ++kt) {
    const int e = (kt < 32) ? lo : hi;
    const int d0 = (kt & 31) * 32;
    __syncthreads();
    {
      float g = (kt < 32) ? g0sh[rA] : g1sh[rA];
      s8v xv = *(const s8v*)&Xb[(size_t)toksh[rA] * 1024 + d0 + cA];
      s8v o;
#pragma unroll
      for (int j = 0; j < 8; ++j) o[j] = (short)bf16_rne(bf2f((u16)xv[j]) * g);
      *(s8v*)&At[rA * 40 + cA] = o;
    }
#pragma unroll
    for (int it = 0; it < 2; ++it) {
      int idx = tid + it * 256;
      int r = idx >> 2, c8 = (idx & 3) << 3;
      *(s8v*)&Bt[r * 40 + c8] = *(const s8v*)&Vw[((size_t)(h * 128 + r) * 8 + e) * 1024 + d0 + c8];
    }
    __syncthreads();
    s8v af[4], bfr[2];
#pragma unroll
    for (int m = 0; m < 4; ++m) af[m] = *(const s8v*)&At[(m * 16 + lr) * 40 + lg * 8];
#pragma unroll
    for (int n = 0; n < 2; ++n) bfr[n] = *(const s8v*)&Bt[(wave * 32 + n * 16 + lr) * 40 + lg * 8];
#pragma unroll
    for (int m = 0; m < 4; ++m)
#pragma unroll
      for (int n = 0; n < 2; ++n)
        acc[m][n] = __builtin_amdgcn_mfma_f32_16x16x32_bf16(af[m], bfr[n], acc[m][n], 0, 0, 0);
  }
#pragma unroll
  for (int m = 0; m < 4; ++m) {
#pragma unroll
    for (int j = 0; j < 4; ++j) {
      int row = m * 16 + lg * 4 + j;
      int ar = tile * 64 + row;
      if (ar < cnt) {
        int tok = toksh[row];
#pragma unroll
        for (int n = 0; n < 2; ++n) {
          int p = wave * 32 + n * 16 + lr;
          Vtmp[(size_t)tok * 1024 + h * 128 + p] = bf16_rne(acc[m][n][j]);
        }
      }
    }
  }
}

// ---------------- transpose Vtmp [t][h*128+p] -> VT [bh][p][s] ----------------
__global__ void vtranspose(const u16* __restrict__ Vtmp, u16* __restrict__ VT) {
  __shared__ u16 tile[64][136];
  const int sb = blockIdx.x, bh = blockIdx.y;
  const int b = bh >> 3, h = bh & 7;
  const int tid = threadIdx.x;
#pragma unroll
  for (int it = 0; it < 4; ++it) {
    int idx = tid + it * 256;
    int r = idx >> 4, c8 = (idx & 15) << 3;
    *(s8v*)&tile[r][c8] = *(const s8v*)&Vtmp[(size_t)(b * 2048 + sb * 64 + r) * 1024 + h * 128 + c8];
  }
  __syncthreads();
#pragma unroll
  for (int it = 0; it < 8; ++it) {
    int idx = tid + it * 256;
    int p = idx >> 4, c4 = (idx & 15) << 2;
    us4 o;
#pragma unroll
    for (int j = 0; j < 4; ++j) o[j] = tile[c4 + j][p];
    *(us4*)&VT[((size_t)bh * 128 + p) * 2048 + sb * 64 + c4] = o;
  }
}

// ---------------- attention (unchanged) ----------------
__global__ __launch_bounds__(256, 2) void attn(
    const u16* __restrict__ Q, const u16* __restrict__ K,
    const u16* __restrict__ VT, u16* __restrict__ CTX) {
  __shared__ u16 Kt[64 * 136];
  __shared__ u16 Vt[128 * 72];
  __shared__ u16 Pl[4][16 * 72];
  const int qb = blockIdx.x, bh = blockIdx.y;
  const int tid = threadIdx.x;
  const int wave = tid >> 6, lane = tid & 63;
  const int lg = lane >> 4, lr = lane & 15;
  const size_t base = (size_t)bh * 2048 * 128;
  const int q0 = qb * 64 + wave * 16;
  s8v qf[4];
#pragma unroll
  for (int ks = 0; ks < 4; ++ks)
    qf[ks] = *(const s8v*)&Q[base + (size_t)(q0 + lr) * 128 + ks * 32 + lg * 8];
  f4v cacc[8] = {};
  float mrun = -1e30f, ssum = 0.f;
  for (int kb = 0; kb < 32; ++kb) {
    __syncthreads();
#pragma unroll
    for (int i = 0; i < 4; ++i) {
      int idx = tid + i * 256;
      int r = idx >> 4, c8 = (idx & 15) << 3;
      *(s8v*)&Kt[r * 136 + c8] = *(const s8v*)&K[base + (size_t)(kb * 64 + r) * 128 + c8];
    }
#pragma unroll
    for (int i = 0; i < 4; ++i) {
      int idx = tid + i * 256;
      int r = idx >> 3, c8 = (idx & 7) << 3;
      *(s8v*)&Vt[r * 72 + c8] = *(const s8v*)&VT[base + (size_t)r * 2048 + kb * 64 + c8];
    }
    __syncthreads();
    f4v sc[4] = {};
#pragma unroll
    for (int ks = 0; ks < 4; ++ks) {
#pragma unroll
      for (int m = 0; m < 4; ++m) {
        s8v ak = *(const s8v*)&Kt[(m * 16 + lr) * 136 + ks * 32 + lg * 8];
        sc[m] = __builtin_amdgcn_mfma_f32_16x16x32_bf16(ak, qf[ks], sc[m], 0, 0, 0);
      }
    }
    float tmax = -1e30f;
#pragma unroll
    for (int m = 0; m < 4; ++m)
#pragma unroll
      for (int j = 0; j < 4; ++j) {
        float v = sc[m][j] * ATT_SCALE;
        sc[m][j] = v;
        tmax = fmaxf(tmax, v);
      }
    tmax = fmaxf(tmax, __shfl_xor(tmax, 16));
    tmax = fmaxf(tmax, __shfl_xor(tmax, 32));
    float mnew = fmaxf(mrun, tmax);
    float f = __expf(mrun - mnew);
    mrun = mnew;
    float psum = 0.f;
#pragma unroll
    for (int m = 0; m < 4; ++m) {
      us4 pk;
#pragma unroll
      for (int j = 0; j < 4; ++j) {
        float pe = __expf(sc[m][j] - mnew);
        psum += pe;
        pk[j] = bf16_rne(pe);
      }
      *(us4*)&Pl[wave][lr * 72 + m * 16 + lg * 4] = pk;
    }
    psum += __shfl_xor(psum, 16);
    psum += __shfl_xor(psum, 32);
    ssum = ssum * f + psum;
#pragma unroll
    for (int mr = 0; mr < 8; ++mr)
#pragma unroll
      for (int j = 0; j < 4; ++j) cacc[mr][j] *= f;
#pragma unroll
    for (int ks = 0; ks < 2; ++ks) {
      s8v bp = *(const s8v*)&Pl[wave][lr * 72 + ks * 32 + lg * 8];
#pragma unroll
      for (int mr = 0; mr < 8; ++mr) {
        s8v av = *(const s8v*)&Vt[(mr * 16 + lr) * 72 + ks * 32 + lg * 8];
        cacc[mr] = __builtin_amdgcn_mfma_f32_16x16x32_bf16(av, bp, cacc[mr], 0, 0, 0);
      }
    }
  }
  float rinv = 1.f / ssum;
#pragma unroll
  for (int mr = 0; mr < 8; ++mr) {
    us4 pk;
#pragma unroll
    for (int j = 0; j < 4; ++j) pk[j] = bf16_rne(cacc[mr][j] * rinv);
    *(us4*)&CTX[base + (size_t)(q0 + lr) * 128 + mr * 16 + lg * 4] = pk;
  }
}

// ---------------- output expert GEMM: dense, split-K over head halves ----------------
// grid (32 tb, 8 db, 2 kh), 512 threads. K=4096 each. fp32 partial out.
__global__ __launch_bounds__(512, 4) void gemm_out(
    const u16* __restrict__ CTX, const u16* __restrict__ Ow /*[d][8192]*/,
    const float* __restrict__ GateO, float* __restrict__ OP0, float* __restrict__ OP1) {
  __shared__ u16 At[128 * 40];
  __shared__ u16 Bt[128 * 40];
  __shared__ float gsh[128 * 32];
  const int tb = blockIdx.x, db = blockIdx.y, kh = blockIdx.z;
  float* OP = kh ? OP1 : OP0;
  const int tid = threadIdx.x;
  for (int i = tid; i < 4096; i += 512)
    gsh[i] = GateO[(size_t)(tb * 128 + (i >> 5)) * 64 + kh * 32 + (i & 31)];
  const int wave = tid >> 6, lane = tid & 63;
  const int wm = wave >> 1, wn = wave & 1;
  const int lg = lane >> 4, lr = lane & 15;
  const int rS = tid >> 2, cS = (tid & 3) << 3;
  f4v acc[2][4] = {};
  for (int kt = 0; kt < 128; ++kt) {
    const int hl = kt >> 2, p0 = (kt & 3) * 32;
    const int h = (kh * 32 + hl) >> 3;
    __syncthreads();
    {
      int t = tb * 128 + rS;
      int b = t >> 11, s = t & 2047;
      s8v cv = *(const s8v*)&CTX[((size_t)(b * 8 + h) * 2048 + s) * 128 + p0 + cS];
      float g = gsh[rS * 32 + hl];
      s8v o;
#pragma unroll
      for (int j = 0; j < 8; ++j) o[j] = (short)bf16_rne(bf2f((u16)cv[j]) * g);
      *(s8v*)&At[rS * 40 + cS] = o;
      *(s8v*)&Bt[rS * 40 + cS] = *(const s8v*)&Ow[(size_t)(db * 128 + rS) * 8192 + kh * 4096 + kt * 32 + cS];
    }
    __syncthreads();
    s8v af[2], bfr[4];
#pragma unroll
    for (int m = 0; m < 2; ++m) af[m] = *(const s8v*)&At[(wm * 32 + m * 16 + lr) * 40 + lg * 8];
#pragma unroll
    for (int n = 0; n < 4; ++n) bfr[n] = *(const s8v*)&Bt[(wn * 64 + n * 16 + lr) * 40 + lg * 8];
#pragma unroll
    for (int m = 0; m < 2; ++m)
#pragma unroll
      for (int n = 0; n < 4; ++n)
        acc[m][n] = __builtin_amdgcn_mfma_f32_16x16x32_bf16(af[m], bfr[n], acc[m][n], 0, 0, 0);
  }
#pragma unroll
  for (int m = 0; m < 2; ++m) {
    int t = tb * 128 + wm * 32 + m * 16 + lg * 4;
#pragma unroll
    for (int n = 0; n < 4; ++n) {
      int d = db * 128 + wn * 64 + n * 16 + lr;
#pragma unroll
      for (int j = 0; j < 4; ++j)
        OP[(size_t)(t + j) * 1024 + d] = acc[m][n][j];
    }
  }
}

__global__ void add_out(const float4* __restrict__ A, const float4* __restrict__ B,
                        float4* __restrict__ O) {
  int i = blockIdx.x * 256 + threadIdx.x;  // 1048576 float4s
  float4 a = A[i], b = B[i];
  O[i] = make_float4(a.x + b.x, a.y + b.y, a.z + b.z, a.w + b.w);
}

extern "C" void kernel_launch(void* const* d_in, const int* in_sizes, int n_in,
                              void* d_out, int out_size, void* d_ws, size_t ws_size,
                              hipStream_t stream) {
  const float* x     = (const float*)d_in[0];
  const float* q_w   = (const float*)d_in[1];
  const float* k_w   = (const float*)d_in[2];
  const float* v_w   = (const float*)d_in[3];
  const float* o_w   = (const float*)d_in[4];
  const float* sel_v = (const float*)d_in[5];
  const float* sel_o = (const float*)d_in[6];
  const float* rs    = (const float*)d_in[7];

  char* ws = (char*)d_ws;
  const size_t MB = 1048576;
  // Region timeline (overlays noted):
  u16*    xb   = (u16*)(ws);                    // 0..8 MB: xb (routing->gemm_v_sparse)
  u16*    ctx  = (u16*)(ws);                    //          ctx (attn->gemm_out) overlays xb
  u16*    qwb  = (u16*)(ws + 8 * MB);           // 2 MB
  u16*    kwb  = (u16*)(ws + 10 * MB);          // 2 MB
  u16*    vwT  = (u16*)(ws + 12 * MB);          // 16 MB [h][p][e][d] (prep->gemm_v_sparse)
  float*  op0  = (float*)(ws + 12 * MB);        // 16 MB f32 partial (gemm_out) overlays vwT
  u16*    owT  = (u16*)(ws + 28 * MB);          // 16 MB [d][8192]
  float*  go   = (float*)(ws + 44 * MB);        // 1 MB dense gate_o
  int2*   tvi  = (int2*)(ws + 45 * MB);         // 256 KB
  float2* tvg  = (float2*)(ws + 45 * MB + 262144);  // 256 KB
  int*    bcnt = (int*)(ws + 45 * MB + 524288); // 1 KB (224 ints)
  int*    btok = (int*)(ws + 45 * MB + 528384); // 896 KB
  float2* bgate= (float2*)(ws + 46 * MB + 524288); // 1.75 MB -> ends < 48.5 MB
  u16*    vtmp = (u16*)(ws + 48 * MB + 524288); // 8 MB [t][h*128+p] (gemm_v_sparse->vtranspose)
  u16*    qh   = (u16*)(ws + 48 * MB + 524288); // 8 MB (gemm_qk->attn) overlays vtmp (after it's dead)
  float*  op1  = (float*)(ws + 48 * MB + 524288); // 16 MB f32 partial, overlays qh+kh after attn
  u16*    kh   = (u16*)(ws + 56 * MB + 524288); // 8 MB
  u16*    vt   = (u16*)(ws + 64 * MB + 524288); // 8 MB [bh][p][s]  -> total 72.5 MB
  float*  outp = (float*)d_out;

  hipLaunchKernelGGL(conv_qk, dim3(2048), dim3(256), 0, stream, q_w, k_w, qwb, kwb);
  hipLaunchKernelGGL(transpose_w, dim3(4, 32, 64), dim3(256), 0, stream, v_w, vwT, 0);
  hipLaunchKernelGGL(transpose_w, dim3(32, 4, 64), dim3(256), 0, stream, o_w, owT, 1);
  hipMemsetAsync(bcnt, 0, 1024, stream);
  hipLaunchKernelGGL(routing, dim3(512), dim3(256), 0, stream, x, sel_v, sel_o, rs, tvi, tvg, go, xb);
  hipLaunchKernelGGL(build_buckets, dim3(16), dim3(256), 0, stream, tvi, tvg, bcnt, btok, bgate);
  hipLaunchKernelGGL(gemm_v_sparse, dim3(8, 224), dim3(256), 0, stream, xb, vwT, bcnt, btok, bgate, vtmp);
  hipLaunchKernelGGL(vtranspose, dim3(32, 16), dim3(256), 0, stream, vtmp, vt);
  hipLaunchKernelGGL(gemm_qk, dim3(32, 8, 2), dim3(256), 0, stream, xb, qwb, kwb, qh, kh);
  hipLaunchKernelGGL(attn, dim3(32, 16), dim3(256), 0, stream, qh, kh, vt, ctx);
  hipLaunchKernelGGL(gemm_out, dim3(32, 8, 2), dim3(512), 0, stream, ctx, owT, go, op0, op1);
  hipLaunchKernelGGL(add_out, dim3(4096), dim3(256), 0, stream, (const float4*)op0, (const float4*)op1, (float4*)outp);
}